// Round 4
// baseline (601.406 us; speedup 1.0000x reference)
//
#include <hip/hip_runtime.h>
#include <cmath>

#define NL 512
#define SS 10
#define DD 128
#define HWC (128 * 128)
#define LDK 36

// ---------------- transpose (D, HW) -> (HW, D), both images ----------------
__global__ __launch_bounds__(256) void transpose_kernel(
    const float* __restrict__ in1, const float* __restrict__ in2,
    float* __restrict__ out1, float* __restrict__ out2)
{
    const float* in = blockIdx.z ? in2 : in1;
    float* out = blockIdx.z ? out2 : out1;
    __shared__ float tile[32][33];
    int hw0 = blockIdx.x * 32;
    int d0 = blockIdx.y * 32;
    int tx = threadIdx.x, ty = threadIdx.y;  // 32 x 8
#pragma unroll
    for (int j = 0; j < 32; j += 8)
        tile[ty + j][tx] = in[(size_t)(d0 + ty + j) * HWC + hw0 + tx];
    __syncthreads();
#pragma unroll
    for (int j = 0; j < 32; j += 8)
        out[(size_t)(hw0 + ty + j) * DD + d0 + tx] = tile[tx][ty + j];
}

// ---------------- sample points + bilinear + normalize ----------------
__device__ __forceinline__ float fetchd(const float* __restrict__ dt, int y, int x, int d)
{
    bool inb = (x >= 0) && (x < 128) && (y >= 0) && (y < 128);
    int yc = y < 0 ? 0 : (y > 127 ? 127 : y);
    int xc = x < 0 ? 0 : (x > 127 ? 127 : x);
    float v = dt[((size_t)(yc * 128 + xc)) * DD + d];
    return inb ? v : 0.0f;
}

__global__ __launch_bounds__(128) void sample_kernel(
    const float* __restrict__ seg1, const float* __restrict__ seg2,
    const float* __restrict__ dt1, const float* __restrict__ dt2,
    float* __restrict__ dd1, float* __restrict__ dd2,
    int* __restrict__ v1, int* __restrict__ v2)
{
#pragma clang fp contract(off)
    int L = blockIdx.x;
    int img = blockIdx.y;
    const float* seg = img ? seg2 : seg1;
    const float* dt = img ? dt2 : dt1;
    float* dd = img ? dd2 : dd1;
    int* vv = img ? v2 : v1;

    float p0y = seg[L * 4 + 0], p0x = seg[L * 4 + 1];
    float p1y = seg[L * 4 + 2], p1x = seg[L * 4 + 3];
    float dy = p0y - p1y, dx = p0x - p1x;
    float len = sqrtf(dy * dy + dx * dx);
    float nf = floorf(len / 8.0f);
    nf = fminf(fmaxf(nf, 2.0f), 10.0f);
    int ni = (int)nf;
    float ivy = (p1y - p0y) / (nf - 1.0f);
    float ivx = (p1x - p0x) / (nf - 1.0f);

    int d = threadIdx.x;
    __shared__ float red[128];

    for (int t = 0; t < SS; ++t) {
        int pt = L * SS + t;
        bool val = t < ni;  // block-uniform
        float outv = 0.0f;
        if (val) {
            float py = p0y + (float)t * ivy;
            float px = p0x + (float)t * ivx;
            float gx = 2.0f * px / 511.0f - 1.0f;
            float gy = 2.0f * py / 511.0f - 1.0f;
            float ix = ((gx + 1.0f) * 128.0f - 1.0f) / 2.0f;
            float iy = ((gy + 1.0f) * 128.0f - 1.0f) / 2.0f;
            float x0f = floorf(ix), y0f = floorf(iy);
            float wx = ix - x0f, wy = iy - y0f;
            int x0 = (int)x0f, y0 = (int)y0f;
            float g00 = fetchd(dt, y0, x0, d);
            float g01 = fetchd(dt, y0, x0 + 1, d);
            float g10 = fetchd(dt, y0 + 1, x0, d);
            float g11 = fetchd(dt, y0 + 1, x0 + 1, d);
            float omwx = 1.0f - wx, omwy = 1.0f - wy;
            float v = g00 * omwy * omwx + g01 * omwy * wx + g10 * wy * omwx + g11 * wy * wx;
            red[d] = v * v;
            __syncthreads();
            for (int s = 64; s > 0; s >>= 1) {
                if (d < s) red[d] += red[d + s];
                __syncthreads();
            }
            float nrm = sqrtf(red[0]);
            outv = v / fmaxf(nrm, 1e-12f);
        }
        dd[(size_t)pt * DD + d] = outv;
        if (d == 0) vv[pt] = val ? 1 : 0;
        __syncthreads();
    }
}

// ---------------- GEMM (16x16 lines per block, 512 thr, 5x10/thread) + line-score ----
// Each thread owns a 5x10 half-block (s in {half*5..half*5+4}) of line pair (iL,jL).
__global__ __launch_bounds__(512, 4) void gemm_ls_kernel(
    const float* __restrict__ d1, const float* __restrict__ d2,
    const int* __restrict__ v1, const int* __restrict__ v2,
    float* __restrict__ ls)
{
    __shared__ float smem[2 * 160 * LDK];  // As | Bs, reused as exchange buffer
    float* As = smem;
    float* Bs = smem + 160 * LDK;

    int tid = threadIdx.x;
    int tx = tid & 15;          // line_j within tile
    int tyh = tid >> 4;         // 0..31 : (line_i, half)
    int li = tyh >> 1;          // line_i within tile
    int half = tyh & 1;         // s-range half
    int bi = blockIdx.y, bj = blockIdx.x;

    float acc[5][10];
#pragma unroll
    for (int i = 0; i < 5; ++i)
#pragma unroll
        for (int j = 0; j < 10; ++j) acc[i][j] = 0.0f;

    int arow0 = li * 10 + half * 5;  // first of this thread's 5 point-rows (block-local)

    for (int kt = 0; kt < 4; ++kt) {
        __syncthreads();
#pragma unroll
        for (int it = 0; it < 3; ++it) {
            int f = tid + it * 512;       // 0..1535, need 0..1279
            if (f < 1280) {
                int row = f >> 3;             // 0..159
                int c4 = (f & 7) << 2;        // 0..28
                float4 a = *(const float4*)&d1[((size_t)(bi * 160 + row)) * DD + kt * 32 + c4];
                *(float4*)&As[row * LDK + c4] = a;
                int pl = row / 10, pts = row - pl * 10;
                int prow = pts * 16 + pl;     // t-major layout for B
                float4 b = *(const float4*)&d2[((size_t)(bj * 160 + row)) * DD + kt * 32 + c4];
                *(float4*)&Bs[prow * LDK + c4] = b;
            }
        }
        __syncthreads();
#pragma unroll
        for (int k4 = 0; k4 < 8; ++k4) {
            float4 av[5];
#pragma unroll
            for (int i = 0; i < 5; ++i)
                av[i] = *(const float4*)&As[(arow0 + i) * LDK + k4 * 4];
#pragma unroll
            for (int j = 0; j < 10; ++j) {
                float4 b = *(const float4*)&Bs[(j * 16 + tx) * LDK + k4 * 4];
#pragma unroll
                for (int i = 0; i < 5; ++i) {
                    acc[i][j] = fmaf(av[i].x, b.x, acc[i][j]);
                    acc[i][j] = fmaf(av[i].y, b.y, acc[i][j]);
                    acc[i][j] = fmaf(av[i].z, b.z, acc[i][j]);
                    acc[i][j] = fmaf(av[i].w, b.w, acc[i][j]);
                }
            }
        }
    }

    // ---- fused line-score epilogue with 2-thread (half) merge ----
    int iL = bi * 16 + li;
    int jL = bj * 16 + tx;
    int va[5], vb[10];
#pragma unroll
    for (int i = 0; i < 5; ++i) va[i] = v1[iL * 10 + half * 5 + i];   // FIXED: global s index
#pragma unroll
    for (int t = 0; t < 10; ++t) vb[t] = v2[jL * 10 + t];

    // partial row stats: this thread's 5 rows are complete in t
    float rsum = 0.0f;
    float rcnt = 0.0f;
#pragma unroll
    for (int i = 0; i < 5; ++i) {
        float mx = -3.0e38f;
#pragma unroll
        for (int t = 0; t < 10; ++t) {
            float v = (va[i] && vb[t]) ? acc[i][t] : -1.0f;
            mx = fmaxf(mx, v);
        }
        if (mx != -1.0f) { rsum += mx; rcnt += 1.0f; }
    }
    // partial col maxes: over this thread's 5 rows only
    float cmax[10];
#pragma unroll
    for (int t = 0; t < 10; ++t) {
        float mx = -3.0e38f;
#pragma unroll
        for (int i = 0; i < 5; ++i) {
            float v = (va[i] && vb[t]) ? acc[i][t] : -1.0f;
            mx = fmaxf(mx, v);
        }
        cmax[t] = mx;
    }

    __syncthreads();  // LDS (As/Bs) no longer needed; reuse as exchange
    float* exch = smem;
#pragma unroll
    for (int t = 0; t < 10; ++t) exch[tid * 13 + t] = cmax[t];
    exch[tid * 13 + 10] = rsum;
    exch[tid * 13 + 11] = rcnt;
    __syncthreads();

    if (half == 0) {
        const float* p = &exch[(tid + 16) * 13];
        float sum1 = rsum + p[10];
        float c1 = rcnt + p[11];
        float sum2 = 0.0f;
        float c2 = 0.0f;
#pragma unroll
        for (int t = 0; t < 10; ++t) {
            float m = fmaxf(cmax[t], p[t]);
            if (m != -1.0f) { sum2 += m; c2 += 1.0f; }
        }
        ls[(size_t)iL * NL + jL] = (sum1 / c1 + sum2 / c2) * 0.5f;
    }
}

// ---------------- top-10: one wave per (line, dir), repeated max-extraction ------
__global__ __launch_bounds__(64) void topk_kernel(
    const float* __restrict__ ls, int* __restrict__ topk)
{
    int i = blockIdx.x;
    int dir = blockIdx.y;
    int lane = threadIdx.x;

    float v[8];
#pragma unroll
    for (int it = 0; it < 8; ++it) {
        int j = it * 64 + lane;
        v[it] = dir ? ls[(size_t)j * NL + i] : ls[(size_t)i * NL + j];
    }
    int* outp = &topk[(size_t)(dir * NL + i) * 10];

    for (int p = 9; p >= 0; --p) {
        float bv = -3.0e38f;
        int bi = -1;
#pragma unroll
        for (int it = 0; it < 8; ++it) {
            int j = it * 64 + lane;
            bool better = (v[it] > bv) || (v[it] == bv && j > bi);
            if (better) { bv = v[it]; bi = j; }
        }
#pragma unroll
        for (int m = 1; m < 64; m <<= 1) {
            float ov = __shfl_xor(bv, m);
            int oi = __shfl_xor(bi, m);
            bool better = (ov > bv) || (ov == bv && oi > bi);
            if (better) { bv = ov; bi = oi; }
        }
        if ((bi & 63) == lane) v[bi >> 6] = -3.0e38f;
        if (lane == 0) outp[p] = bi;
    }
}

// ---------------- Needleman-Wunsch on 10x10 blocks of top-10 candidates ----------
__global__ __launch_bounds__(128) void nw_kernel(
    const float* __restrict__ d1, const float* __restrict__ d2,
    const int* __restrict__ v1, const int* __restrict__ v2,
    const int* __restrict__ topk, float* __restrict__ nwout)
{
    int L = blockIdx.x;
    int dir = blockIdx.y;
    const float* Ad = dir ? d2 : d1;
    const float* Bd = dir ? d1 : d2;
    const int* vA = dir ? v2 : v1;
    const int* vB = dir ? v1 : v2;
    const int* tk = topk + (size_t)(dir * NL + L) * 10;

    __shared__ float Asl[10 * 132];
    __shared__ float Bsl[10 * 132];
    __shared__ float M[10][110];  // [cand][s*11+t]
    __shared__ int vam[10];

    int tid = threadIdx.x;
#pragma unroll
    for (int it = 0; it < 10; ++it) {
        int idx = tid + it * 128;
        int row = idx >> 7, col = idx & 127;
        Asl[row * 132 + col] = Ad[((size_t)L * 10 + row) * DD + col];
    }
    if (tid < 10) vam[tid] = vA[L * 10 + tid];

    for (int c = 0; c < 10; ++c) {
        int j = tk[c];
        __syncthreads();
#pragma unroll
        for (int it = 0; it < 10; ++it) {
            int idx = tid + it * 128;
            int row = idx >> 7, col = idx & 127;
            Bsl[row * 132 + col] = Bd[((size_t)j * 10 + row) * DD + col];
        }
        __syncthreads();
        if (tid < 100) {
            int s = tid / 10, t = tid - s * 10;
            const float4* ap = (const float4*)&Asl[s * 132];
            const float4* bp = (const float4*)&Bsl[t * 132];
            float acc = 0.0f;
#pragma unroll
            for (int k = 0; k < 32; ++k) {
                float4 a = ap[k], b = bp[k];
                acc = fmaf(a.x, b.x, acc);
                acc = fmaf(a.y, b.y, acc);
                acc = fmaf(a.z, b.z, acc);
                acc = fmaf(a.w, b.w, acc);
            }
            int ok = vam[s] && vB[j * 10 + t];
            M[c][s * 11 + t] = ok ? acc : -1.0f;
        }
    }
    __syncthreads();

    if (tid < 20) {
        int c = tid % 10, f = tid / 10;
        float prev[11];
#pragma unroll
        for (int p = 0; p < 11; ++p) prev[p] = 0.0f;
#pragma unroll
        for (int s = 0; s < 10; ++s) {
            float oldp = prev[0];
            float run = -3.0e38f;
#pragma unroll
            for (int t = 0; t < 10; ++t) {
                int tt = f ? (9 - t) : t;
                float sc = M[c][s * 11 + tt] - 0.1f;
                float pt1 = prev[t + 1];
                float av = fmaxf(pt1, oldp + sc);
                run = fmaxf(run, av);
                prev[t + 1] = fmaxf(run, 0.0f);
                oldp = pt1;
            }
        }
        nwout[((size_t)(dir * NL + L)) * 20 + f * 10 + c] = prev[10];
    }
}

// ---------------- argmax + mutual check ----------------
__global__ __launch_bounds__(512) void final_kernel(
    const float* __restrict__ nw, const int* __restrict__ topk, int* __restrict__ out)
{
    __shared__ int m1[NL], m2[NL];
    int t = threadIdx.x;
    {
        const float* p = nw + (size_t)t * 20;
        float bb = -3.0e38f; int kk = 0;
        for (int k = 0; k < 20; ++k) {
            float v = p[k];
            if (v > bb) { bb = v; kk = k; }
        }
        m1[t] = topk[(size_t)t * 10 + (kk % 10)];
    }
    {
        const float* p = nw + (size_t)(NL + t) * 20;
        float bb = -3.0e38f; int kk = 0;
        for (int k = 0; k < 20; ++k) {
            float v = p[k];
            if (v > bb) { bb = v; kk = k; }
        }
        m2[t] = topk[(size_t)(NL + t) * 10 + (kk % 10)];
    }
    __syncthreads();
    int mt = m1[t];
    out[t] = (m2[mt] == t) ? mt : -1;
}

extern "C" void kernel_launch(void* const* d_in, const int* in_sizes, int n_in,
                              void* d_out, int out_size, void* d_ws, size_t ws_size,
                              hipStream_t stream)
{
    const float* seg1 = (const float*)d_in[0];
    const float* seg2 = (const float*)d_in[1];
    const float* desc1 = (const float*)d_in[2];
    const float* desc2 = (const float*)d_in[3];
    int* out = (int*)d_out;

    char* ws = (char*)d_ws;
    size_t off = 0;
    float* dt1 = (float*)(ws + off); off += (size_t)DD * HWC * 4;        // 8 MB
    float* dt2 = (float*)(ws + off); off += (size_t)DD * HWC * 4;        // 8 MB
    float* dd1 = (float*)(ws + off); off += (size_t)NL * SS * DD * 4;    // 2.5 MB
    float* dd2 = (float*)(ws + off); off += (size_t)NL * SS * DD * 4;    // 2.5 MB
    int* v1 = (int*)(ws + off); off += (size_t)NL * SS * 4;
    int* v2 = (int*)(ws + off); off += (size_t)NL * SS * 4;
    float* ls = (float*)(ws + off); off += (size_t)NL * NL * 4;          // 1 MB
    int* topk = (int*)(ws + off); off += (size_t)2 * NL * 10 * 4;
    float* nwv = (float*)(ws + off); off += (size_t)2 * NL * 20 * 4;

    transpose_kernel<<<dim3(HWC / 32, DD / 32, 2), dim3(32, 8), 0, stream>>>(
        desc1, desc2, dt1, dt2);
    sample_kernel<<<dim3(NL, 2), 128, 0, stream>>>(
        seg1, seg2, dt1, dt2, dd1, dd2, v1, v2);
    gemm_ls_kernel<<<dim3(32, 32), 512, 0, stream>>>(dd1, dd2, v1, v2, ls);
    topk_kernel<<<dim3(NL, 2), 64, 0, stream>>>(ls, topk);
    nw_kernel<<<dim3(NL, 2), 128, 0, stream>>>(dd1, dd2, v1, v2, topk, nwv);
    final_kernel<<<1, 512, 0, stream>>>(nwv, topk, out);
}

// Round 5
// 288.543 us; speedup vs baseline: 2.0843x; 2.0843x over previous
//
#include <hip/hip_runtime.h>
#include <cmath>

#define NL 512
#define SS 10
#define DD 128
#define HWC (128 * 128)
#define NPTS (NL * SS * DD)   // 655360 elements per image descriptor set

typedef __attribute__((ext_vector_type(8))) short short8;
typedef __attribute__((ext_vector_type(4))) float f32x4;

// ---------------- transpose (D, HW) -> (HW, D), both images ----------------
__global__ __launch_bounds__(256) void transpose_kernel(
    const float* __restrict__ in1, const float* __restrict__ in2,
    float* __restrict__ out1, float* __restrict__ out2)
{
    const float* in = blockIdx.z ? in2 : in1;
    float* out = blockIdx.z ? out2 : out1;
    __shared__ float tile[32][33];
    int hw0 = blockIdx.x * 32;
    int d0 = blockIdx.y * 32;
    int tx = threadIdx.x, ty = threadIdx.y;  // 32 x 8
#pragma unroll
    for (int j = 0; j < 32; j += 8)
        tile[ty + j][tx] = in[(size_t)(d0 + ty + j) * HWC + hw0 + tx];
    __syncthreads();
#pragma unroll
    for (int j = 0; j < 32; j += 8)
        out[(size_t)(hw0 + ty + j) * DD + d0 + tx] = tile[tx][ty + j];
}

// ---------------- sample points + bilinear + normalize ----------------
__device__ __forceinline__ float fetchd(const float* __restrict__ dt, int y, int x, int d)
{
    bool inb = (x >= 0) && (x < 128) && (y >= 0) && (y < 128);
    int yc = y < 0 ? 0 : (y > 127 ? 127 : y);
    int xc = x < 0 ? 0 : (x > 127 ? 127 : x);
    float v = dt[((size_t)(yc * 128 + xc)) * DD + d];
    return inb ? v : 0.0f;
}

__global__ __launch_bounds__(128) void sample_kernel(
    const float* __restrict__ seg1, const float* __restrict__ seg2,
    const float* __restrict__ dt1, const float* __restrict__ dt2,
    float* __restrict__ dd1, float* __restrict__ dd2,
    int* __restrict__ v1, int* __restrict__ v2)
{
#pragma clang fp contract(off)
    int L = blockIdx.x;
    int img = blockIdx.y;
    const float* seg = img ? seg2 : seg1;
    const float* dt = img ? dt2 : dt1;
    float* dd = img ? dd2 : dd1;
    int* vv = img ? v2 : v1;

    float p0y = seg[L * 4 + 0], p0x = seg[L * 4 + 1];
    float p1y = seg[L * 4 + 2], p1x = seg[L * 4 + 3];
    float dy = p0y - p1y, dx = p0x - p1x;
    float len = sqrtf(dy * dy + dx * dx);
    float nf = floorf(len / 8.0f);
    nf = fminf(fmaxf(nf, 2.0f), 10.0f);
    int ni = (int)nf;
    float ivy = (p1y - p0y) / (nf - 1.0f);
    float ivx = (p1x - p0x) / (nf - 1.0f);

    int d = threadIdx.x;
    __shared__ float red[128];

    for (int t = 0; t < SS; ++t) {
        int pt = L * SS + t;
        bool val = t < ni;  // block-uniform
        float outv = 0.0f;
        if (val) {
            float py = p0y + (float)t * ivy;
            float px = p0x + (float)t * ivx;
            float gx = 2.0f * px / 511.0f - 1.0f;
            float gy = 2.0f * py / 511.0f - 1.0f;
            float ix = ((gx + 1.0f) * 128.0f - 1.0f) / 2.0f;
            float iy = ((gy + 1.0f) * 128.0f - 1.0f) / 2.0f;
            float x0f = floorf(ix), y0f = floorf(iy);
            float wx = ix - x0f, wy = iy - y0f;
            int x0 = (int)x0f, y0 = (int)y0f;
            float g00 = fetchd(dt, y0, x0, d);
            float g01 = fetchd(dt, y0, x0 + 1, d);
            float g10 = fetchd(dt, y0 + 1, x0, d);
            float g11 = fetchd(dt, y0 + 1, x0 + 1, d);
            float omwx = 1.0f - wx, omwy = 1.0f - wy;
            float v = g00 * omwy * omwx + g01 * omwy * wx + g10 * wy * omwx + g11 * wy * wx;
            red[d] = v * v;
            __syncthreads();
            for (int s = 64; s > 0; s >>= 1) {
                if (d < s) red[d] += red[d + s];
                __syncthreads();
            }
            float nrm = sqrtf(red[0]);
            outv = v / fmaxf(nrm, 1e-12f);
        }
        dd[(size_t)pt * DD + d] = outv;
        if (d == 0) vv[pt] = val ? 1 : 0;
        __syncthreads();
    }
}

// ---------------- split fp32 -> bf16 hi + bf16 lo planes ----------------
__device__ __forceinline__ unsigned short f2bf_rne(float x)
{
    union { float f; unsigned u; } c; c.f = x;
    unsigned r = c.u + 0x7fffu + ((c.u >> 16) & 1u);
    return (unsigned short)(r >> 16);
}
__device__ __forceinline__ float bf2f(unsigned short b)
{
    union { unsigned u; float f; } c; c.u = ((unsigned)b) << 16;
    return c.f;
}

__global__ __launch_bounds__(256) void pack_kernel(
    const float* __restrict__ dd1, const float* __restrict__ dd2,
    unsigned short* __restrict__ dh1, unsigned short* __restrict__ dl1,
    unsigned short* __restrict__ dh2, unsigned short* __restrict__ dl2)
{
    int i = blockIdx.x * 256 + threadIdx.x;  // NPTS total
    float a = dd1[i];
    unsigned short h = f2bf_rne(a);
    dh1[i] = h;
    dl1[i] = f2bf_rne(a - bf2f(h));
    float b = dd2[i];
    unsigned short h2 = f2bf_rne(b);
    dh2[i] = h2;
    dl2[i] = f2bf_rne(b - bf2f(h2));
}

// ---------------- MFMA GEMM (16x16 lines per block) + fused line-score ----------
// Block: 160x160 points, 320 threads = 5 waves; wave w owns rows [32w,32w+32)
// as two 16-row strips x 10 column tiles of mfma_f32_16x16x32_bf16.
// Split-bf16: score = ah.bh + al.bh + ah.bl  (al.bl dropped, ~2^-18 rel).
#define LSTR 40   // shorts per LDS plane row (32 data + 8 pad; 80B, 16B-aligned frags)
__global__ __launch_bounds__(320) void gemm_ls_kernel(
    const unsigned short* __restrict__ dh1, const unsigned short* __restrict__ dl1,
    const unsigned short* __restrict__ dh2, const unsigned short* __restrict__ dl2,
    const int* __restrict__ v1, const int* __restrict__ v2,
    float* __restrict__ ls)
{
    __shared__ unsigned int smemU[12800];  // 51200 B: 4 planes of 160*LSTR shorts
    unsigned short* Ahi = (unsigned short*)smemU;
    unsigned short* Alo = Ahi + 160 * LSTR;
    unsigned short* Bhi = Ahi + 2 * 160 * LSTR;
    unsigned short* Blo = Ahi + 3 * 160 * LSTR;
    float* Msc = (float*)smemU;            // epilogue reuse: 40 x 164 floats

    int tid = threadIdx.x;
    int lane = tid & 63;
    int w = tid >> 6;          // wave 0..4
    int quad = lane >> 4;      // k-quarter
    int lrow = lane & 15;      // m (A) / n (B) within tile
    int bi = blockIdx.y, bj = blockIdx.x;

    f32x4 acc[2][10];
#pragma unroll
    for (int s = 0; s < 2; ++s)
#pragma unroll
        for (int j = 0; j < 10; ++j)
#pragma unroll
            for (int r = 0; r < 4; ++r) acc[s][j][r] = 0.0f;

    for (int kt = 0; kt < 4; ++kt) {
        __syncthreads();
        // stage 4 planes: 160 rows x 32 shorts each = 640 uint4 per plane
#pragma unroll
        for (int pl = 0; pl < 4; ++pl) {
            const unsigned short* g = (pl == 0) ? dh1 : (pl == 1) ? dl1 : (pl == 2) ? dh2 : dl2;
            unsigned short* l = (pl == 0) ? Ahi : (pl == 1) ? Alo : (pl == 2) ? Bhi : Blo;
            int base = (pl < 2 ? bi : bj) * 160;
#pragma unroll
            for (int it = 0; it < 2; ++it) {
                int f = tid + it * 320;        // 0..639
                int row = f >> 2;              // 0..159
                int c = f & 3;                 // uint4 within row
                *(uint4*)&l[row * LSTR + c * 8] =
                    *(const uint4*)&g[(size_t)(base + row) * DD + kt * 32 + c * 8];
            }
        }
        __syncthreads();

        short8 ah0 = *(const short8*)&Ahi[(w * 32 + lrow) * LSTR + quad * 8];
        short8 al0 = *(const short8*)&Alo[(w * 32 + lrow) * LSTR + quad * 8];
        short8 ah1 = *(const short8*)&Ahi[(w * 32 + 16 + lrow) * LSTR + quad * 8];
        short8 al1 = *(const short8*)&Alo[(w * 32 + 16 + lrow) * LSTR + quad * 8];
#pragma unroll
        for (int j = 0; j < 10; ++j) {
            short8 bh = *(const short8*)&Bhi[(j * 16 + lrow) * LSTR + quad * 8];
            short8 bl = *(const short8*)&Blo[(j * 16 + lrow) * LSTR + quad * 8];
            acc[0][j] = __builtin_amdgcn_mfma_f32_16x16x32_bf16(ah0, bh, acc[0][j], 0, 0, 0);
            acc[0][j] = __builtin_amdgcn_mfma_f32_16x16x32_bf16(al0, bh, acc[0][j], 0, 0, 0);
            acc[0][j] = __builtin_amdgcn_mfma_f32_16x16x32_bf16(ah0, bl, acc[0][j], 0, 0, 0);
            acc[1][j] = __builtin_amdgcn_mfma_f32_16x16x32_bf16(ah1, bh, acc[1][j], 0, 0, 0);
            acc[1][j] = __builtin_amdgcn_mfma_f32_16x16x32_bf16(al1, bh, acc[1][j], 0, 0, 0);
            acc[1][j] = __builtin_amdgcn_mfma_f32_16x16x32_bf16(ah1, bl, acc[1][j], 0, 0, 0);
        }
    }

    // ---- epilogue: 4 phases of 40 rows (= 4 whole lines each) ----
    for (int p = 0; p < 4; ++p) {
        __syncthreads();
        // dump this phase's C rows to LDS (C/D layout: col=lane&15, row=quad*4+reg)
#pragma unroll
        for (int s = 0; s < 2; ++s)
#pragma unroll
            for (int j = 0; j < 10; ++j)
#pragma unroll
                for (int r = 0; r < 4; ++r) {
                    int gr = w * 32 + s * 16 + quad * 4 + r;
                    int lr = gr - 40 * p;
                    if (lr >= 0 && lr < 40)
                        Msc[lr * 164 + j * 16 + lrow] = acc[s][j][r];
                }
        __syncthreads();
        if (tid < 64) {
            int li4 = tid >> 4;        // line within phase (0..3)
            int lj = tid & 15;         // line_j within tile
            int iL = bi * 16 + p * 4 + li4;
            int jL = bj * 16 + lj;
            int va[10], vb[10];
#pragma unroll
            for (int i = 0; i < 10; ++i) va[i] = v1[iL * 10 + i];
#pragma unroll
            for (int t = 0; t < 10; ++t) vb[t] = v2[jL * 10 + t];

            float sum1 = 0.0f; int c1 = 0;
#pragma unroll
            for (int i = 0; i < 10; ++i) {
                float mx = -3.0e38f;
#pragma unroll
                for (int t = 0; t < 10; ++t) {
                    float v = (va[i] && vb[t]) ? Msc[(li4 * 10 + i) * 164 + lj * 10 + t] : -1.0f;
                    mx = fmaxf(mx, v);
                }
                if (mx != -1.0f) { sum1 += mx; c1++; }
            }
            float sum2 = 0.0f; int c2 = 0;
#pragma unroll
            for (int t = 0; t < 10; ++t) {
                float mx = -3.0e38f;
#pragma unroll
                for (int i = 0; i < 10; ++i) {
                    float v = (va[i] && vb[t]) ? Msc[(li4 * 10 + i) * 164 + lj * 10 + t] : -1.0f;
                    mx = fmaxf(mx, v);
                }
                if (mx != -1.0f) { sum2 += mx; c2++; }
            }
            ls[(size_t)iL * NL + jL] = (sum1 / (float)c1 + sum2 / (float)c2) * 0.5f;
        }
    }
}

// ---------------- top-10: one wave per (line, dir), repeated max-extraction ------
__global__ __launch_bounds__(64) void topk_kernel(
    const float* __restrict__ ls, int* __restrict__ topk)
{
    int i = blockIdx.x;
    int dir = blockIdx.y;
    int lane = threadIdx.x;

    float v[8];
#pragma unroll
    for (int it = 0; it < 8; ++it) {
        int j = it * 64 + lane;
        v[it] = dir ? ls[(size_t)j * NL + i] : ls[(size_t)i * NL + j];
    }
    int* outp = &topk[(size_t)(dir * NL + i) * 10];

    for (int p = 9; p >= 0; --p) {
        float bv = -3.0e38f;
        int bi = -1;
#pragma unroll
        for (int it = 0; it < 8; ++it) {
            int j = it * 64 + lane;
            bool better = (v[it] > bv) || (v[it] == bv && j > bi);
            if (better) { bv = v[it]; bi = j; }
        }
#pragma unroll
        for (int m = 1; m < 64; m <<= 1) {
            float ov = __shfl_xor(bv, m);
            int oi = __shfl_xor(bi, m);
            bool better = (ov > bv) || (ov == bv && oi > bi);
            if (better) { bv = ov; bi = oi; }
        }
        if ((bi & 63) == lane) v[bi >> 6] = -3.0e38f;
        if (lane == 0) outp[p] = bi;
    }
}

// ---------------- Needleman-Wunsch on 10x10 blocks of top-10 candidates ----------
__global__ __launch_bounds__(128) void nw_kernel(
    const float* __restrict__ d1, const float* __restrict__ d2,
    const int* __restrict__ v1, const int* __restrict__ v2,
    const int* __restrict__ topk, float* __restrict__ nwout)
{
    int L = blockIdx.x;
    int dir = blockIdx.y;
    const float* Ad = dir ? d2 : d1;
    const float* Bd = dir ? d1 : d2;
    const int* vA = dir ? v2 : v1;
    const int* vB = dir ? v1 : v2;
    const int* tk = topk + (size_t)(dir * NL + L) * 10;

    __shared__ float Asl[10 * 132];
    __shared__ float Bsl[10 * 132];
    __shared__ float M[10][110];  // [cand][s*11+t]
    __shared__ int vam[10];

    int tid = threadIdx.x;
#pragma unroll
    for (int it = 0; it < 10; ++it) {
        int idx = tid + it * 128;
        int row = idx >> 7, col = idx & 127;
        Asl[row * 132 + col] = Ad[((size_t)L * 10 + row) * DD + col];
    }
    if (tid < 10) vam[tid] = vA[L * 10 + tid];

    for (int c = 0; c < 10; ++c) {
        int j = tk[c];
        __syncthreads();
#pragma unroll
        for (int it = 0; it < 10; ++it) {
            int idx = tid + it * 128;
            int row = idx >> 7, col = idx & 127;
            Bsl[row * 132 + col] = Bd[((size_t)j * 10 + row) * DD + col];
        }
        __syncthreads();
        if (tid < 100) {
            int s = tid / 10, t = tid - s * 10;
            const float4* ap = (const float4*)&Asl[s * 132];
            const float4* bp = (const float4*)&Bsl[t * 132];
            float acc = 0.0f;
#pragma unroll
            for (int k = 0; k < 32; ++k) {
                float4 a = ap[k], b = bp[k];
                acc = fmaf(a.x, b.x, acc);
                acc = fmaf(a.y, b.y, acc);
                acc = fmaf(a.z, b.z, acc);
                acc = fmaf(a.w, b.w, acc);
            }
            int ok = vam[s] && vB[j * 10 + t];
            M[c][s * 11 + t] = ok ? acc : -1.0f;
        }
    }
    __syncthreads();

    if (tid < 20) {
        int c = tid % 10, f = tid / 10;
        float prev[11];
#pragma unroll
        for (int p = 0; p < 11; ++p) prev[p] = 0.0f;
#pragma unroll
        for (int s = 0; s < 10; ++s) {
            float oldp = prev[0];
            float run = -3.0e38f;
#pragma unroll
            for (int t = 0; t < 10; ++t) {
                int tt = f ? (9 - t) : t;
                float sc = M[c][s * 11 + tt] - 0.1f;
                float pt1 = prev[t + 1];
                float av = fmaxf(pt1, oldp + sc);
                run = fmaxf(run, av);
                prev[t + 1] = fmaxf(run, 0.0f);
                oldp = pt1;
            }
        }
        nwout[((size_t)(dir * NL + L)) * 20 + f * 10 + c] = prev[10];
    }
}

// ---------------- argmax + mutual check ----------------
__global__ __launch_bounds__(512) void final_kernel(
    const float* __restrict__ nw, const int* __restrict__ topk, int* __restrict__ out)
{
    __shared__ int m1[NL], m2[NL];
    int t = threadIdx.x;
    {
        const float* p = nw + (size_t)t * 20;
        float bb = -3.0e38f; int kk = 0;
        for (int k = 0; k < 20; ++k) {
            float v = p[k];
            if (v > bb) { bb = v; kk = k; }
        }
        m1[t] = topk[(size_t)t * 10 + (kk % 10)];
    }
    {
        const float* p = nw + (size_t)(NL + t) * 20;
        float bb = -3.0e38f; int kk = 0;
        for (int k = 0; k < 20; ++k) {
            float v = p[k];
            if (v > bb) { bb = v; kk = k; }
        }
        m2[t] = topk[(size_t)(NL + t) * 10 + (kk % 10)];
    }
    __syncthreads();
    int mt = m1[t];
    out[t] = (m2[mt] == t) ? mt : -1;
}

extern "C" void kernel_launch(void* const* d_in, const int* in_sizes, int n_in,
                              void* d_out, int out_size, void* d_ws, size_t ws_size,
                              hipStream_t stream)
{
    const float* seg1 = (const float*)d_in[0];
    const float* seg2 = (const float*)d_in[1];
    const float* desc1 = (const float*)d_in[2];
    const float* desc2 = (const float*)d_in[3];
    int* out = (int*)d_out;

    char* ws = (char*)d_ws;
    size_t off = 0;
    float* dt1 = (float*)(ws + off); off += (size_t)DD * HWC * 4;        // 8 MB
    float* dt2 = (float*)(ws + off); off += (size_t)DD * HWC * 4;        // 8 MB
    float* dd1 = (float*)(ws + off); off += (size_t)NPTS * 4;            // 2.5 MB
    float* dd2 = (float*)(ws + off); off += (size_t)NPTS * 4;            // 2.5 MB
    int* v1 = (int*)(ws + off); off += (size_t)NL * SS * 4;
    int* v2 = (int*)(ws + off); off += (size_t)NL * SS * 4;
    float* ls = (float*)(ws + off); off += (size_t)NL * NL * 4;          // 1 MB
    int* topk = (int*)(ws + off); off += (size_t)2 * NL * 10 * 4;
    float* nwv = (float*)(ws + off); off += (size_t)2 * NL * 20 * 4;

    // bf16 hi/lo planes live in the dt1/dt2 regions (dead after sample_kernel)
    unsigned short* dh1 = (unsigned short*)dt1;
    unsigned short* dl1 = dh1 + NPTS;
    unsigned short* dh2 = (unsigned short*)dt2;
    unsigned short* dl2 = dh2 + NPTS;

    transpose_kernel<<<dim3(HWC / 32, DD / 32, 2), dim3(32, 8), 0, stream>>>(
        desc1, desc2, dt1, dt2);
    sample_kernel<<<dim3(NL, 2), 128, 0, stream>>>(
        seg1, seg2, dt1, dt2, dd1, dd2, v1, v2);
    pack_kernel<<<NPTS / 256, 256, 0, stream>>>(dd1, dd2, dh1, dl1, dh2, dl2);
    gemm_ls_kernel<<<dim3(32, 32), 320, 0, stream>>>(dh1, dl1, dh2, dl2, v1, v2, ls);
    topk_kernel<<<dim3(NL, 2), 64, 0, stream>>>(ls, topk);
    nw_kernel<<<dim3(NL, 2), 128, 0, stream>>>(dd1, dd2, v1, v2, topk, nwv);
    final_kernel<<<1, 512, 0, stream>>>(nwv, topk, out);
}

// Round 6
// 269.365 us; speedup vs baseline: 2.2327x; 1.0712x over previous
//
#include <hip/hip_runtime.h>
#include <cmath>

#define NL 512
#define SS 10
#define DD 128
#define HWC (128 * 128)
#define NPTS (NL * SS * DD)   // 655360 elements per image descriptor set

typedef __attribute__((ext_vector_type(8))) short short8;
typedef __attribute__((ext_vector_type(4))) float f32x4;

// ---------------- transpose (D, HW) -> (HW, D), both images ----------------
__global__ __launch_bounds__(256) void transpose_kernel(
    const float* __restrict__ in1, const float* __restrict__ in2,
    float* __restrict__ out1, float* __restrict__ out2)
{
    const float* in = blockIdx.z ? in2 : in1;
    float* out = blockIdx.z ? out2 : out1;
    __shared__ float tile[32][33];
    int hw0 = blockIdx.x * 32;
    int d0 = blockIdx.y * 32;
    int tx = threadIdx.x, ty = threadIdx.y;  // 32 x 8
#pragma unroll
    for (int j = 0; j < 32; j += 8)
        tile[ty + j][tx] = in[(size_t)(d0 + ty + j) * HWC + hw0 + tx];
    __syncthreads();
#pragma unroll
    for (int j = 0; j < 32; j += 8)
        out[(size_t)(hw0 + ty + j) * DD + d0 + tx] = tile[tx][ty + j];
}

// ---------------- sample points + bilinear + normalize ----------------
__device__ __forceinline__ float fetchd(const float* __restrict__ dt, int y, int x, int d)
{
    bool inb = (x >= 0) && (x < 128) && (y >= 0) && (y < 128);
    int yc = y < 0 ? 0 : (y > 127 ? 127 : y);
    int xc = x < 0 ? 0 : (x > 127 ? 127 : x);
    float v = dt[((size_t)(yc * 128 + xc)) * DD + d];
    return inb ? v : 0.0f;
}

__global__ __launch_bounds__(128) void sample_kernel(
    const float* __restrict__ seg1, const float* __restrict__ seg2,
    const float* __restrict__ dt1, const float* __restrict__ dt2,
    float* __restrict__ dd1, float* __restrict__ dd2,
    int* __restrict__ v1, int* __restrict__ v2)
{
#pragma clang fp contract(off)
    int L = blockIdx.x;
    int img = blockIdx.y;
    const float* seg = img ? seg2 : seg1;
    const float* dt = img ? dt2 : dt1;
    float* dd = img ? dd2 : dd1;
    int* vv = img ? v2 : v1;

    float p0y = seg[L * 4 + 0], p0x = seg[L * 4 + 1];
    float p1y = seg[L * 4 + 2], p1x = seg[L * 4 + 3];
    float dy = p0y - p1y, dx = p0x - p1x;
    float len = sqrtf(dy * dy + dx * dx);
    float nf = floorf(len / 8.0f);
    nf = fminf(fmaxf(nf, 2.0f), 10.0f);
    int ni = (int)nf;
    float ivy = (p1y - p0y) / (nf - 1.0f);
    float ivx = (p1x - p0x) / (nf - 1.0f);

    int d = threadIdx.x;
    __shared__ float red[128];

    for (int t = 0; t < SS; ++t) {
        int pt = L * SS + t;
        bool val = t < ni;  // block-uniform
        float outv = 0.0f;
        if (val) {
            float py = p0y + (float)t * ivy;
            float px = p0x + (float)t * ivx;
            float gx = 2.0f * px / 511.0f - 1.0f;
            float gy = 2.0f * py / 511.0f - 1.0f;
            float ix = ((gx + 1.0f) * 128.0f - 1.0f) / 2.0f;
            float iy = ((gy + 1.0f) * 128.0f - 1.0f) / 2.0f;
            float x0f = floorf(ix), y0f = floorf(iy);
            float wx = ix - x0f, wy = iy - y0f;
            int x0 = (int)x0f, y0 = (int)y0f;
            float g00 = fetchd(dt, y0, x0, d);
            float g01 = fetchd(dt, y0, x0 + 1, d);
            float g10 = fetchd(dt, y0 + 1, x0, d);
            float g11 = fetchd(dt, y0 + 1, x0 + 1, d);
            float omwx = 1.0f - wx, omwy = 1.0f - wy;
            float v = g00 * omwy * omwx + g01 * omwy * wx + g10 * wy * omwx + g11 * wy * wx;
            red[d] = v * v;
            __syncthreads();
            for (int s = 64; s > 0; s >>= 1) {
                if (d < s) red[d] += red[d + s];
                __syncthreads();
            }
            float nrm = sqrtf(red[0]);
            outv = v / fmaxf(nrm, 1e-12f);
        }
        dd[(size_t)pt * DD + d] = outv;
        if (d == 0) vv[pt] = val ? 1 : 0;
        __syncthreads();
    }
}

// ---------------- split fp32 -> bf16 hi + bf16 lo planes ----------------
__device__ __forceinline__ unsigned short f2bf_rne(float x)
{
    union { float f; unsigned u; } c; c.f = x;
    unsigned r = c.u + 0x7fffu + ((c.u >> 16) & 1u);
    return (unsigned short)(r >> 16);
}
__device__ __forceinline__ float bf2f(unsigned short b)
{
    union { unsigned u; float f; } c; c.u = ((unsigned)b) << 16;
    return c.f;
}

__global__ __launch_bounds__(256) void pack_kernel(
    const float* __restrict__ dd1, const float* __restrict__ dd2,
    unsigned short* __restrict__ dh1, unsigned short* __restrict__ dl1,
    unsigned short* __restrict__ dh2, unsigned short* __restrict__ dl2)
{
    int i = blockIdx.x * 256 + threadIdx.x;  // NPTS total
    float a = dd1[i];
    unsigned short h = f2bf_rne(a);
    dh1[i] = h;
    dl1[i] = f2bf_rne(a - bf2f(h));
    float b = dd2[i];
    unsigned short h2 = f2bf_rne(b);
    dh2[i] = h2;
    dl2[i] = f2bf_rne(b - bf2f(h2));
}

// ---------------- MFMA GEMM (16x16 lines per block, 640 thr) + line-score ------
// 10 waves; wave w owns C rows [16w,16w+16) x 10 col-tiles (acc = 40 VGPR).
// Register-prefetch double buffer over kt; split-bf16: ah.bh + al.bh + ah.bl.
#define LSTR 40   // shorts per LDS plane row (32 data + 8 pad)
__global__ __launch_bounds__(640) void gemm_ls_kernel(
    const unsigned short* __restrict__ dh1, const unsigned short* __restrict__ dl1,
    const unsigned short* __restrict__ dh2, const unsigned short* __restrict__ dl2,
    const int* __restrict__ v1, const int* __restrict__ v2,
    float* __restrict__ ls)
{
    __shared__ char smem[80 * 164 * 4];     // 52480 B: staging planes | Msc
    __shared__ int vmA[160], vmB[160];      // validity masks (persist)
    unsigned short* Ahi = (unsigned short*)smem;
    unsigned short* Alo = Ahi + 160 * LSTR;
    unsigned short* Bhi = Ahi + 2 * 160 * LSTR;
    unsigned short* Blo = Ahi + 3 * 160 * LSTR;
    float* Msc = (float*)smem;              // epilogue: 80 x 164 floats

    int tid = threadIdx.x;
    int lane = tid & 63;
    int w = tid >> 6;          // wave 0..9
    int quad = lane >> 4;      // k-quarter / C row group
    int lrow = lane & 15;      // m (A) / n (B) within tile
    int bi = blockIdx.y, bj = blockIdx.x;

    if (tid < 160) vmA[tid] = v1[bi * 160 + tid];
    else if (tid < 320) vmB[tid - 160] = v2[bj * 160 + (tid - 160)];

    f32x4 acc[10];
#pragma unroll
    for (int j = 0; j < 10; ++j)
#pragma unroll
        for (int r = 0; r < 4; ++r) acc[j][r] = 0.0f;

    // staging assignment: thread -> (row, chunk) for each of 4 planes
    int srow = tid >> 2;       // 0..159
    int sc = tid & 3;          // uint4 within 32-short row segment
    const unsigned short* gAh = dh1 + (size_t)(bi * 160 + srow) * DD + sc * 8;
    const unsigned short* gAl = dl1 + (size_t)(bi * 160 + srow) * DD + sc * 8;
    const unsigned short* gBh = dh2 + (size_t)(bj * 160 + srow) * DD + sc * 8;
    const unsigned short* gBl = dl2 + (size_t)(bj * 160 + srow) * DD + sc * 8;
    unsigned short* wAh = &Ahi[srow * LSTR + sc * 8];
    unsigned short* wAl = &Alo[srow * LSTR + sc * 8];
    unsigned short* wBh = &Bhi[srow * LSTR + sc * 8];
    unsigned short* wBl = &Blo[srow * LSTR + sc * 8];

    uint4 pf0 = *(const uint4*)(gAh);
    uint4 pf1 = *(const uint4*)(gAl);
    uint4 pf2 = *(const uint4*)(gBh);
    uint4 pf3 = *(const uint4*)(gBl);

    for (int kt = 0; kt < 4; ++kt) {
        *(uint4*)wAh = pf0;
        *(uint4*)wAl = pf1;
        *(uint4*)wBh = pf2;
        *(uint4*)wBl = pf3;
        __syncthreads();
        if (kt < 3) {  // issue next-kt loads; latency hidden by MFMA below
            pf0 = *(const uint4*)(gAh + (kt + 1) * 32);
            pf1 = *(const uint4*)(gAl + (kt + 1) * 32);
            pf2 = *(const uint4*)(gBh + (kt + 1) * 32);
            pf3 = *(const uint4*)(gBl + (kt + 1) * 32);
        }
        short8 ah = *(const short8*)&Ahi[(w * 16 + lrow) * LSTR + quad * 8];
        short8 al = *(const short8*)&Alo[(w * 16 + lrow) * LSTR + quad * 8];
#pragma unroll
        for (int j = 0; j < 10; ++j) {
            short8 bh = *(const short8*)&Bhi[(j * 16 + lrow) * LSTR + quad * 8];
            short8 bl = *(const short8*)&Blo[(j * 16 + lrow) * LSTR + quad * 8];
            acc[j] = __builtin_amdgcn_mfma_f32_16x16x32_bf16(ah, bh, acc[j], 0, 0, 0);
            acc[j] = __builtin_amdgcn_mfma_f32_16x16x32_bf16(al, bh, acc[j], 0, 0, 0);
            acc[j] = __builtin_amdgcn_mfma_f32_16x16x32_bf16(ah, bl, acc[j], 0, 0, 0);
        }
        __syncthreads();  // all frag reads done before next staging overwrite
    }

    // ---- epilogue: 2 phases of 80 rows (8 lines), 128 reducer threads each ----
    for (int p = 0; p < 2; ++p) {
        __syncthreads();
        if (w >= p * 5 && w < p * 5 + 5) {
            int lr0 = (w - p * 5) * 16 + quad * 4;
#pragma unroll
            for (int j = 0; j < 10; ++j)
#pragma unroll
                for (int r = 0; r < 4; ++r)
                    Msc[(lr0 + r) * 164 + j * 16 + lrow] = acc[j][r];
        }
        __syncthreads();
        if (tid < 128) {
            int li = tid >> 4;         // line within phase (0..7)
            int lj = tid & 15;
            int iL = bi * 16 + p * 8 + li;
            int jL = bj * 16 + lj;
            int va[10], vb[10];
#pragma unroll
            for (int i = 0; i < 10; ++i) va[i] = vmA[(p * 8 + li) * 10 + i];
#pragma unroll
            for (int t = 0; t < 10; ++t) vb[t] = vmB[lj * 10 + t];

            float sum1 = 0.0f; int c1 = 0;
#pragma unroll
            for (int i = 0; i < 10; ++i) {
                float mx = -3.0e38f;
#pragma unroll
                for (int t = 0; t < 10; ++t) {
                    float v = (va[i] && vb[t]) ? Msc[(li * 10 + i) * 164 + lj * 10 + t] : -1.0f;
                    mx = fmaxf(mx, v);
                }
                if (mx != -1.0f) { sum1 += mx; c1++; }
            }
            float sum2 = 0.0f; int c2 = 0;
#pragma unroll
            for (int t = 0; t < 10; ++t) {
                float mx = -3.0e38f;
#pragma unroll
                for (int i = 0; i < 10; ++i) {
                    float v = (va[i] && vb[t]) ? Msc[(li * 10 + i) * 164 + lj * 10 + t] : -1.0f;
                    mx = fmaxf(mx, v);
                }
                if (mx != -1.0f) { sum2 += mx; c2++; }
            }
            ls[(size_t)iL * NL + jL] = (sum1 / (float)c1 + sum2 / (float)c2) * 0.5f;
        }
    }
}

// ---------------- top-10: one wave per (line, dir), repeated max-extraction ------
__global__ __launch_bounds__(64) void topk_kernel(
    const float* __restrict__ ls, int* __restrict__ topk)
{
    int i = blockIdx.x;
    int dir = blockIdx.y;
    int lane = threadIdx.x;

    float v[8];
#pragma unroll
    for (int it = 0; it < 8; ++it) {
        int j = it * 64 + lane;
        v[it] = dir ? ls[(size_t)j * NL + i] : ls[(size_t)i * NL + j];
    }
    int* outp = &topk[(size_t)(dir * NL + i) * 10];

    for (int p = 9; p >= 0; --p) {
        float bv = -3.0e38f;
        int bi = -1;
#pragma unroll
        for (int it = 0; it < 8; ++it) {
            int j = it * 64 + lane;
            bool better = (v[it] > bv) || (v[it] == bv && j > bi);
            if (better) { bv = v[it]; bi = j; }
        }
#pragma unroll
        for (int m = 1; m < 64; m <<= 1) {
            float ov = __shfl_xor(bv, m);
            int oi = __shfl_xor(bi, m);
            bool better = (ov > bv) || (ov == bv && oi > bi);
            if (better) { bv = ov; bi = oi; }
        }
        if ((bi & 63) == lane) v[bi >> 6] = -3.0e38f;
        if (lane == 0) outp[p] = bi;
    }
}

// ---------------- Needleman-Wunsch on 10x10 blocks of top-10 candidates ----------
__global__ __launch_bounds__(128) void nw_kernel(
    const float* __restrict__ d1, const float* __restrict__ d2,
    const int* __restrict__ v1, const int* __restrict__ v2,
    const int* __restrict__ topk, float* __restrict__ nwout)
{
    int L = blockIdx.x;
    int dir = blockIdx.y;
    const float* Ad = dir ? d2 : d1;
    const float* Bd = dir ? d1 : d2;
    const int* vA = dir ? v2 : v1;
    const int* vB = dir ? v1 : v2;
    const int* tk = topk + (size_t)(dir * NL + L) * 10;

    __shared__ float Asl[10 * 132];
    __shared__ float Bsl[10 * 132];
    __shared__ float M[10][110];  // [cand][s*11+t]
    __shared__ int vam[10];

    int tid = threadIdx.x;
#pragma unroll
    for (int it = 0; it < 10; ++it) {
        int idx = tid + it * 128;
        int row = idx >> 7, col = idx & 127;
        Asl[row * 132 + col] = Ad[((size_t)L * 10 + row) * DD + col];
    }
    if (tid < 10) vam[tid] = vA[L * 10 + tid];

    for (int c = 0; c < 10; ++c) {
        int j = tk[c];
        __syncthreads();
#pragma unroll
        for (int it = 0; it < 10; ++it) {
            int idx = tid + it * 128;
            int row = idx >> 7, col = idx & 127;
            Bsl[row * 132 + col] = Bd[((size_t)j * 10 + row) * DD + col];
        }
        __syncthreads();
        if (tid < 100) {
            int s = tid / 10, t = tid - s * 10;
            const float4* ap = (const float4*)&Asl[s * 132];
            const float4* bp = (const float4*)&Bsl[t * 132];
            float acc = 0.0f;
#pragma unroll
            for (int k = 0; k < 32; ++k) {
                float4 a = ap[k], b = bp[k];
                acc = fmaf(a.x, b.x, acc);
                acc = fmaf(a.y, b.y, acc);
                acc = fmaf(a.z, b.z, acc);
                acc = fmaf(a.w, b.w, acc);
            }
            int ok = vam[s] && vB[j * 10 + t];
            M[c][s * 11 + t] = ok ? acc : -1.0f;
        }
    }
    __syncthreads();

    if (tid < 20) {
        int c = tid % 10, f = tid / 10;
        float prev[11];
#pragma unroll
        for (int p = 0; p < 11; ++p) prev[p] = 0.0f;
#pragma unroll
        for (int s = 0; s < 10; ++s) {
            float oldp = prev[0];
            float run = -3.0e38f;
#pragma unroll
            for (int t = 0; t < 10; ++t) {
                int tt = f ? (9 - t) : t;
                float sc = M[c][s * 11 + tt] - 0.1f;
                float pt1 = prev[t + 1];
                float av = fmaxf(pt1, oldp + sc);
                run = fmaxf(run, av);
                prev[t + 1] = fmaxf(run, 0.0f);
                oldp = pt1;
            }
        }
        nwout[((size_t)(dir * NL + L)) * 20 + f * 10 + c] = prev[10];
    }
}

// ---------------- argmax + mutual check ----------------
__global__ __launch_bounds__(512) void final_kernel(
    const float* __restrict__ nw, const int* __restrict__ topk, int* __restrict__ out)
{
    __shared__ int m1[NL], m2[NL];
    int t = threadIdx.x;
    {
        const float* p = nw + (size_t)t * 20;
        float bb = -3.0e38f; int kk = 0;
        for (int k = 0; k < 20; ++k) {
            float v = p[k];
            if (v > bb) { bb = v; kk = k; }
        }
        m1[t] = topk[(size_t)t * 10 + (kk % 10)];
    }
    {
        const float* p = nw + (size_t)(NL + t) * 20;
        float bb = -3.0e38f; int kk = 0;
        for (int k = 0; k < 20; ++k) {
            float v = p[k];
            if (v > bb) { bb = v; kk = k; }
        }
        m2[t] = topk[(size_t)(NL + t) * 10 + (kk % 10)];
    }
    __syncthreads();
    int mt = m1[t];
    out[t] = (m2[mt] == t) ? mt : -1;
}

extern "C" void kernel_launch(void* const* d_in, const int* in_sizes, int n_in,
                              void* d_out, int out_size, void* d_ws, size_t ws_size,
                              hipStream_t stream)
{
    const float* seg1 = (const float*)d_in[0];
    const float* seg2 = (const float*)d_in[1];
    const float* desc1 = (const float*)d_in[2];
    const float* desc2 = (const float*)d_in[3];
    int* out = (int*)d_out;

    char* ws = (char*)d_ws;
    size_t off = 0;
    float* dt1 = (float*)(ws + off); off += (size_t)DD * HWC * 4;        // 8 MB
    float* dt2 = (float*)(ws + off); off += (size_t)DD * HWC * 4;        // 8 MB
    float* dd1 = (float*)(ws + off); off += (size_t)NPTS * 4;            // 2.5 MB
    float* dd2 = (float*)(ws + off); off += (size_t)NPTS * 4;            // 2.5 MB
    int* v1 = (int*)(ws + off); off += (size_t)NL * SS * 4;
    int* v2 = (int*)(ws + off); off += (size_t)NL * SS * 4;
    float* ls = (float*)(ws + off); off += (size_t)NL * NL * 4;          // 1 MB
    int* topk = (int*)(ws + off); off += (size_t)2 * NL * 10 * 4;
    float* nwv = (float*)(ws + off); off += (size_t)2 * NL * 20 * 4;

    // bf16 hi/lo planes live in the dt1/dt2 regions (dead after sample_kernel)
    unsigned short* dh1 = (unsigned short*)dt1;
    unsigned short* dl1 = dh1 + NPTS;
    unsigned short* dh2 = (unsigned short*)dt2;
    unsigned short* dl2 = dh2 + NPTS;

    transpose_kernel<<<dim3(HWC / 32, DD / 32, 2), dim3(32, 8), 0, stream>>>(
        desc1, desc2, dt1, dt2);
    sample_kernel<<<dim3(NL, 2), 128, 0, stream>>>(
        seg1, seg2, dt1, dt2, dd1, dd2, v1, v2);
    pack_kernel<<<NPTS / 256, 256, 0, stream>>>(dd1, dd2, dh1, dl1, dh2, dl2);
    gemm_ls_kernel<<<dim3(32, 32), 640, 0, stream>>>(dh1, dl1, dh2, dl2, v1, v2, ls);
    topk_kernel<<<dim3(NL, 2), 64, 0, stream>>>(ls, topk);
    nw_kernel<<<dim3(NL, 2), 128, 0, stream>>>(dd1, dd2, v1, v2, topk, nwv);
    final_kernel<<<1, 512, 0, stream>>>(nwv, topk, out);
}

// Round 7
// 249.315 us; speedup vs baseline: 2.4122x; 1.0804x over previous
//
#include <hip/hip_runtime.h>
#include <cmath>

#define NL 512
#define SS 10
#define DD 128
#define HWC (128 * 128)
#define NPTS (NL * SS * DD)   // 655360 elements per image descriptor set

typedef __attribute__((ext_vector_type(8))) short short8;
typedef __attribute__((ext_vector_type(4))) float f32x4;

// ---------------- transpose (D, HW) -> (HW, D), both images ----------------
__global__ __launch_bounds__(256) void transpose_kernel(
    const float* __restrict__ in1, const float* __restrict__ in2,
    float* __restrict__ out1, float* __restrict__ out2)
{
    const float* in = blockIdx.z ? in2 : in1;
    float* out = blockIdx.z ? out2 : out1;
    __shared__ float tile[32][33];
    int hw0 = blockIdx.x * 32;
    int d0 = blockIdx.y * 32;
    int tx = threadIdx.x, ty = threadIdx.y;  // 32 x 8
#pragma unroll
    for (int j = 0; j < 32; j += 8)
        tile[ty + j][tx] = in[(size_t)(d0 + ty + j) * HWC + hw0 + tx];
    __syncthreads();
#pragma unroll
    for (int j = 0; j < 32; j += 8)
        out[(size_t)(hw0 + ty + j) * DD + d0 + tx] = tile[tx][ty + j];
}

// ---------------- sample points + bilinear + normalize ----------------
__device__ __forceinline__ float fetchd(const float* __restrict__ dt, int y, int x, int d)
{
    bool inb = (x >= 0) && (x < 128) && (y >= 0) && (y < 128);
    int yc = y < 0 ? 0 : (y > 127 ? 127 : y);
    int xc = x < 0 ? 0 : (x > 127 ? 127 : x);
    float v = dt[((size_t)(yc * 128 + xc)) * DD + d];
    return inb ? v : 0.0f;
}

__global__ __launch_bounds__(128) void sample_kernel(
    const float* __restrict__ seg1, const float* __restrict__ seg2,
    const float* __restrict__ dt1, const float* __restrict__ dt2,
    float* __restrict__ dd1, float* __restrict__ dd2,
    int* __restrict__ v1, int* __restrict__ v2)
{
#pragma clang fp contract(off)
    int L = blockIdx.x;
    int img = blockIdx.y;
    const float* seg = img ? seg2 : seg1;
    const float* dt = img ? dt2 : dt1;
    float* dd = img ? dd2 : dd1;
    int* vv = img ? v2 : v1;

    float p0y = seg[L * 4 + 0], p0x = seg[L * 4 + 1];
    float p1y = seg[L * 4 + 2], p1x = seg[L * 4 + 3];
    float dy = p0y - p1y, dx = p0x - p1x;
    float len = sqrtf(dy * dy + dx * dx);
    float nf = floorf(len / 8.0f);
    nf = fminf(fmaxf(nf, 2.0f), 10.0f);
    int ni = (int)nf;
    float ivy = (p1y - p0y) / (nf - 1.0f);
    float ivx = (p1x - p0x) / (nf - 1.0f);

    int d = threadIdx.x;
    __shared__ float red[128];

    for (int t = 0; t < SS; ++t) {
        int pt = L * SS + t;
        bool val = t < ni;  // block-uniform
        float outv = 0.0f;
        if (val) {
            float py = p0y + (float)t * ivy;
            float px = p0x + (float)t * ivx;
            float gx = 2.0f * px / 511.0f - 1.0f;
            float gy = 2.0f * py / 511.0f - 1.0f;
            float ix = ((gx + 1.0f) * 128.0f - 1.0f) / 2.0f;
            float iy = ((gy + 1.0f) * 128.0f - 1.0f) / 2.0f;
            float x0f = floorf(ix), y0f = floorf(iy);
            float wx = ix - x0f, wy = iy - y0f;
            int x0 = (int)x0f, y0 = (int)y0f;
            float g00 = fetchd(dt, y0, x0, d);
            float g01 = fetchd(dt, y0, x0 + 1, d);
            float g10 = fetchd(dt, y0 + 1, x0, d);
            float g11 = fetchd(dt, y0 + 1, x0 + 1, d);
            float omwx = 1.0f - wx, omwy = 1.0f - wy;
            float v = g00 * omwy * omwx + g01 * omwy * wx + g10 * wy * omwx + g11 * wy * wx;
            red[d] = v * v;
            __syncthreads();
            for (int s = 64; s > 0; s >>= 1) {
                if (d < s) red[d] += red[d + s];
                __syncthreads();
            }
            float nrm = sqrtf(red[0]);
            outv = v / fmaxf(nrm, 1e-12f);
        }
        dd[(size_t)pt * DD + d] = outv;
        if (d == 0) vv[pt] = val ? 1 : 0;
        __syncthreads();
    }
}

// ---------------- split fp32 -> bf16 hi + bf16 lo planes ----------------
__device__ __forceinline__ unsigned short f2bf_rne(float x)
{
    union { float f; unsigned u; } c; c.f = x;
    unsigned r = c.u + 0x7fffu + ((c.u >> 16) & 1u);
    return (unsigned short)(r >> 16);
}
__device__ __forceinline__ float bf2f(unsigned short b)
{
    union { unsigned u; float f; } c; c.u = ((unsigned)b) << 16;
    return c.f;
}

__global__ __launch_bounds__(256) void pack_kernel(
    const float* __restrict__ dd1, const float* __restrict__ dd2,
    unsigned short* __restrict__ dh1, unsigned short* __restrict__ dl1,
    unsigned short* __restrict__ dh2, unsigned short* __restrict__ dl2)
{
    int i = blockIdx.x * 256 + threadIdx.x;  // NPTS total
    float a = dd1[i];
    unsigned short h = f2bf_rne(a);
    dh1[i] = h;
    dl1[i] = f2bf_rne(a - bf2f(h));
    float b = dd2[i];
    unsigned short h2 = f2bf_rne(b);
    dh2[i] = h2;
    dl2[i] = f2bf_rne(b - bf2f(h2));
}

// ---------------- MFMA GEMM (16x16 lines per block, 640 thr) + line-score ------
// 10 waves; wave w owns C rows [16w,16w+16) x 10 col-tiles (acc = 40 VGPR).
// Staging via global_load_lds (async DMA, no VGPR round-trip, no prefetch regs).
// LDS plane rows are 32 shorts (64 B), NO pad: required so DMA dest is
// wave-uniform-base + lane*16 (lane l -> row 16w+(l>>2), col (l&3)*8 shorts).
// Epilogue phases over COLUMN tiles: all waves dump uniformly (no divergence,
// so acc has no reason to spill).
__device__ __forceinline__ void gload_lds16(const unsigned short* g, unsigned short* l)
{
    __builtin_amdgcn_global_load_lds(
        (const __attribute__((address_space(1))) void*)g,
        (__attribute__((address_space(3))) void*)l, 16, 0, 0);
}

__global__ __launch_bounds__(640) void gemm_ls_kernel(
    const unsigned short* __restrict__ dh1, const unsigned short* __restrict__ dl1,
    const unsigned short* __restrict__ dh2, const unsigned short* __restrict__ dl2,
    const int* __restrict__ v1, const int* __restrict__ v2,
    float* __restrict__ ls)
{
    __shared__ char smem[160 * 84 * 4];   // 53760 B; staging (40960 B) | Msc
    __shared__ int vmA[160], vmB[160];
    unsigned short* Ahi = (unsigned short*)smem;          // 160 x 32 shorts
    unsigned short* Alo = Ahi + 160 * 32;
    unsigned short* Bhi = Ahi + 2 * 160 * 32;
    unsigned short* Blo = Ahi + 3 * 160 * 32;
    float* Msc = (float*)smem;                            // 160 x 84 floats

    int tid = threadIdx.x;
    int lane = tid & 63;
    int w = tid >> 6;          // wave 0..9
    int quad = lane >> 4;
    int lrow = lane & 15;
    int bi = blockIdx.y, bj = blockIdx.x;

    if (tid < 160) vmA[tid] = v1[bi * 160 + tid];
    else if (tid < 320) vmB[tid - 160] = v2[bj * 160 + (tid - 160)];

    f32x4 acc[10];
#pragma unroll
    for (int j = 0; j < 10; ++j)
#pragma unroll
        for (int r = 0; r < 4; ++r) acc[j][r] = 0.0f;

    // staging: wave w covers rows [16w,16w+16) of each plane; lane l -> row
    // 16w+(l>>2), 16B chunk (l&3). Global addr per lane; LDS dest wave-uniform.
    int grow = w * 16 + (lane >> 2);
    int gcol = (lane & 3) * 8;  // shorts
    const unsigned short* gAh = dh1 + (size_t)(bi * 160 + grow) * DD + gcol;
    const unsigned short* gAl = dl1 + (size_t)(bi * 160 + grow) * DD + gcol;
    const unsigned short* gBh = dh2 + (size_t)(bj * 160 + grow) * DD + gcol;
    const unsigned short* gBl = dl2 + (size_t)(bj * 160 + grow) * DD + gcol;
    unsigned short* lAh = Ahi + w * 512;   // w*1024 bytes
    unsigned short* lAl = Alo + w * 512;
    unsigned short* lBh = Bhi + w * 512;
    unsigned short* lBl = Blo + w * 512;

    for (int kt = 0; kt < 4; ++kt) {
        gload_lds16(gAh + kt * 32, lAh);
        gload_lds16(gAl + kt * 32, lAl);
        gload_lds16(gBh + kt * 32, lBh);
        gload_lds16(gBl + kt * 32, lBl);
        __syncthreads();   // drains vmcnt -> staging complete

        short8 ah = *(const short8*)&Ahi[(w * 16 + lrow) * 32 + quad * 8];
        short8 al = *(const short8*)&Alo[(w * 16 + lrow) * 32 + quad * 8];
#pragma unroll
        for (int j = 0; j < 10; ++j) {
            short8 bh = *(const short8*)&Bhi[(j * 16 + lrow) * 32 + quad * 8];
            short8 bl = *(const short8*)&Blo[(j * 16 + lrow) * 32 + quad * 8];
            acc[j] = __builtin_amdgcn_mfma_f32_16x16x32_bf16(ah, bh, acc[j], 0, 0, 0);
            acc[j] = __builtin_amdgcn_mfma_f32_16x16x32_bf16(al, bh, acc[j], 0, 0, 0);
            acc[j] = __builtin_amdgcn_mfma_f32_16x16x32_bf16(ah, bl, acc[j], 0, 0, 0);
        }
        __syncthreads();   // frag reads done before next staging overwrite
    }

    // ---- epilogue: 2 phases over column-tile halves; all waves dump uniformly ----
#pragma unroll
    for (int p = 0; p < 2; ++p) {
        __syncthreads();
#pragma unroll
        for (int jj = 0; jj < 5; ++jj)
#pragma unroll
            for (int r = 0; r < 4; ++r)
                Msc[(w * 16 + quad * 4 + r) * 84 + jj * 16 + lrow] = acc[p * 5 + jj][r];
        __syncthreads();
        if (tid < 128) {
            int li = tid >> 3;          // i-line 0..15
            int lj8 = tid & 7;          // j-line within phase 0..7
            int iL = bi * 16 + li;
            int jL = bj * 16 + p * 8 + lj8;
            int va[10], vb[10];
#pragma unroll
            for (int i = 0; i < 10; ++i) va[i] = vmA[li * 10 + i];
#pragma unroll
            for (int t = 0; t < 10; ++t) vb[t] = vmB[(p * 8 + lj8) * 10 + t];

            float sum1 = 0.0f; int c1 = 0;
#pragma unroll
            for (int i = 0; i < 10; ++i) {
                float mx = -3.0e38f;
#pragma unroll
                for (int t = 0; t < 10; ++t) {
                    float v = (va[i] && vb[t]) ? Msc[(li * 10 + i) * 84 + lj8 * 10 + t] : -1.0f;
                    mx = fmaxf(mx, v);
                }
                if (mx != -1.0f) { sum1 += mx; c1++; }
            }
            float sum2 = 0.0f; int c2 = 0;
#pragma unroll
            for (int t = 0; t < 10; ++t) {
                float mx = -3.0e38f;
#pragma unroll
                for (int i = 0; i < 10; ++i) {
                    float v = (va[i] && vb[t]) ? Msc[(li * 10 + i) * 84 + lj8 * 10 + t] : -1.0f;
                    mx = fmaxf(mx, v);
                }
                if (mx != -1.0f) { sum2 += mx; c2++; }
            }
            ls[(size_t)iL * NL + jL] = (sum1 / (float)c1 + sum2 / (float)c2) * 0.5f;
        }
    }
}

// ---------------- top-10: one wave per (line, dir), repeated max-extraction ------
__global__ __launch_bounds__(64) void topk_kernel(
    const float* __restrict__ ls, int* __restrict__ topk)
{
    int i = blockIdx.x;
    int dir = blockIdx.y;
    int lane = threadIdx.x;

    float v[8];
#pragma unroll
    for (int it = 0; it < 8; ++it) {
        int j = it * 64 + lane;
        v[it] = dir ? ls[(size_t)j * NL + i] : ls[(size_t)i * NL + j];
    }
    int* outp = &topk[(size_t)(dir * NL + i) * 10];

    for (int p = 9; p >= 0; --p) {
        float bv = -3.0e38f;
        int bi = -1;
#pragma unroll
        for (int it = 0; it < 8; ++it) {
            int j = it * 64 + lane;
            bool better = (v[it] > bv) || (v[it] == bv && j > bi);
            if (better) { bv = v[it]; bi = j; }
        }
#pragma unroll
        for (int m = 1; m < 64; m <<= 1) {
            float ov = __shfl_xor(bv, m);
            int oi = __shfl_xor(bi, m);
            bool better = (ov > bv) || (ov == bv && oi > bi);
            if (better) { bv = ov; bi = oi; }
        }
        if ((bi & 63) == lane) v[bi >> 6] = -3.0e38f;
        if (lane == 0) outp[p] = bi;
    }
}

// ---------------- Needleman-Wunsch on 10x10 blocks of top-10 candidates ----------
__global__ __launch_bounds__(128) void nw_kernel(
    const float* __restrict__ d1, const float* __restrict__ d2,
    const int* __restrict__ v1, const int* __restrict__ v2,
    const int* __restrict__ topk, float* __restrict__ nwout)
{
    int L = blockIdx.x;
    int dir = blockIdx.y;
    const float* Ad = dir ? d2 : d1;
    const float* Bd = dir ? d1 : d2;
    const int* vA = dir ? v2 : v1;
    const int* vB = dir ? v1 : v2;
    const int* tk = topk + (size_t)(dir * NL + L) * 10;

    __shared__ float Asl[10 * 132];
    __shared__ float Bsl[10 * 132];
    __shared__ float M[10][110];  // [cand][s*11+t]
    __shared__ int vam[10];

    int tid = threadIdx.x;
#pragma unroll
    for (int it = 0; it < 10; ++it) {
        int idx = tid + it * 128;
        int row = idx >> 7, col = idx & 127;
        Asl[row * 132 + col] = Ad[((size_t)L * 10 + row) * DD + col];
    }
    if (tid < 10) vam[tid] = vA[L * 10 + tid];

    for (int c = 0; c < 10; ++c) {
        int j = tk[c];
        __syncthreads();
#pragma unroll
        for (int it = 0; it < 10; ++it) {
            int idx = tid + it * 128;
            int row = idx >> 7, col = idx & 127;
            Bsl[row * 132 + col] = Bd[((size_t)j * 10 + row) * DD + col];
        }
        __syncthreads();
        if (tid < 100) {
            int s = tid / 10, t = tid - s * 10;
            const float4* ap = (const float4*)&Asl[s * 132];
            const float4* bp = (const float4*)&Bsl[t * 132];
            float acc = 0.0f;
#pragma unroll
            for (int k = 0; k < 32; ++k) {
                float4 a = ap[k], b = bp[k];
                acc = fmaf(a.x, b.x, acc);
                acc = fmaf(a.y, b.y, acc);
                acc = fmaf(a.z, b.z, acc);
                acc = fmaf(a.w, b.w, acc);
            }
            int ok = vam[s] && vB[j * 10 + t];
            M[c][s * 11 + t] = ok ? acc : -1.0f;
        }
    }
    __syncthreads();

    if (tid < 20) {
        int c = tid % 10, f = tid / 10;
        float prev[11];
#pragma unroll
        for (int p = 0; p < 11; ++p) prev[p] = 0.0f;
#pragma unroll
        for (int s = 0; s < 10; ++s) {
            float oldp = prev[0];
            float run = -3.0e38f;
#pragma unroll
            for (int t = 0; t < 10; ++t) {
                int tt = f ? (9 - t) : t;
                float sc = M[c][s * 11 + tt] - 0.1f;
                float pt1 = prev[t + 1];
                float av = fmaxf(pt1, oldp + sc);
                run = fmaxf(run, av);
                prev[t + 1] = fmaxf(run, 0.0f);
                oldp = pt1;
            }
        }
        nwout[((size_t)(dir * NL + L)) * 20 + f * 10 + c] = prev[10];
    }
}

// ---------------- argmax + mutual check ----------------
__global__ __launch_bounds__(512) void final_kernel(
    const float* __restrict__ nw, const int* __restrict__ topk, int* __restrict__ out)
{
    __shared__ int m1[NL], m2[NL];
    int t = threadIdx.x;
    {
        const float* p = nw + (size_t)t * 20;
        float bb = -3.0e38f; int kk = 0;
        for (int k = 0; k < 20; ++k) {
            float v = p[k];
            if (v > bb) { bb = v; kk = k; }
        }
        m1[t] = topk[(size_t)t * 10 + (kk % 10)];
    }
    {
        const float* p = nw + (size_t)(NL + t) * 20;
        float bb = -3.0e38f; int kk = 0;
        for (int k = 0; k < 20; ++k) {
            float v = p[k];
            if (v > bb) { bb = v; kk = k; }
        }
        m2[t] = topk[(size_t)(NL + t) * 10 + (kk % 10)];
    }
    __syncthreads();
    int mt = m1[t];
    out[t] = (m2[mt] == t) ? mt : -1;
}

extern "C" void kernel_launch(void* const* d_in, const int* in_sizes, int n_in,
                              void* d_out, int out_size, void* d_ws, size_t ws_size,
                              hipStream_t stream)
{
    const float* seg1 = (const float*)d_in[0];
    const float* seg2 = (const float*)d_in[1];
    const float* desc1 = (const float*)d_in[2];
    const float* desc2 = (const float*)d_in[3];
    int* out = (int*)d_out;

    char* ws = (char*)d_ws;
    size_t off = 0;
    float* dt1 = (float*)(ws + off); off += (size_t)DD * HWC * 4;        // 8 MB
    float* dt2 = (float*)(ws + off); off += (size_t)DD * HWC * 4;        // 8 MB
    float* dd1 = (float*)(ws + off); off += (size_t)NPTS * 4;            // 2.5 MB
    float* dd2 = (float*)(ws + off); off += (size_t)NPTS * 4;            // 2.5 MB
    int* v1 = (int*)(ws + off); off += (size_t)NL * SS * 4;
    int* v2 = (int*)(ws + off); off += (size_t)NL * SS * 4;
    float* ls = (float*)(ws + off); off += (size_t)NL * NL * 4;          // 1 MB
    int* topk = (int*)(ws + off); off += (size_t)2 * NL * 10 * 4;
    float* nwv = (float*)(ws + off); off += (size_t)2 * NL * 20 * 4;

    // bf16 hi/lo planes live in the dt1/dt2 regions (dead after sample_kernel)
    unsigned short* dh1 = (unsigned short*)dt1;
    unsigned short* dl1 = dh1 + NPTS;
    unsigned short* dh2 = (unsigned short*)dt2;
    unsigned short* dl2 = dh2 + NPTS;

    transpose_kernel<<<dim3(HWC / 32, DD / 32, 2), dim3(32, 8), 0, stream>>>(
        desc1, desc2, dt1, dt2);
    sample_kernel<<<dim3(NL, 2), 128, 0, stream>>>(
        seg1, seg2, dt1, dt2, dd1, dd2, v1, v2);
    pack_kernel<<<NPTS / 256, 256, 0, stream>>>(dd1, dd2, dh1, dl1, dh2, dl2);
    gemm_ls_kernel<<<dim3(32, 32), 640, 0, stream>>>(dh1, dl1, dh2, dl2, v1, v2, ls);
    topk_kernel<<<dim3(NL, 2), 64, 0, stream>>>(ls, topk);
    nw_kernel<<<dim3(NL, 2), 128, 0, stream>>>(dd1, dd2, v1, v2, topk, nwv);
    final_kernel<<<1, 512, 0, stream>>>(nwv, topk, out);
}